// Round 1
// baseline (1898.818 us; speedup 1.0000x reference)
//
#include <hip/hip_runtime.h>

#define B 4
#define N1 2048
#define N2 8192
#define C1 128
#define C2 64
#define K 15
#define F 128
#define S 16
#define Q 32   // queries per conv block

// ---------------------------------------------------------------------------
// Kernel 1: exact kNN (top-16 of 2048) per query point.
// One thread per query; xyz1 for the batch staged in LDS (24 KB).
// fp contract OFF + numpy reduction order so distance bits match the
// reference exactly -> identical neighbor selection even at near-ties.
// ---------------------------------------------------------------------------
__global__ __launch_bounds__(256) void knn_kernel(const float* __restrict__ xyz1,
                                                  const float* __restrict__ xyz2,
                                                  int* __restrict__ nn_idx) {
#pragma clang fp contract(off)
  __shared__ float sx[N1], sy[N1], sz[N1];
  const int b = blockIdx.y;
  const float* p1 = xyz1 + (size_t)b * N1 * 3;
  for (int i = threadIdx.x; i < N1; i += 256) {
    sx[i] = p1[i * 3 + 0];
    sy[i] = p1[i * 3 + 1];
    sz[i] = p1[i * 3 + 2];
  }
  __syncthreads();

  const int q = blockIdx.x * 256 + threadIdx.x;
  const float* p2 = xyz2 + ((size_t)b * N2 + q) * 3;
  const float qx = p2[0], qy = p2[1], qz = p2[2];

  float bd[S];
  int bi[S];
#pragma unroll
  for (int j = 0; j < S; ++j) { bd[j] = 3.4e38f; bi[j] = 0; }

#pragma unroll 4
  for (int i = 0; i < N1; ++i) {
    float dx = qx - sx[i];
    float dy = qy - sy[i];
    float dz = qz - sz[i];
    float d = dx * dx;
    d = d + dy * dy;
    d = d + dz * dz;
    // strict < : on exact ties keep the incumbent (lower index) -> matches
    // lax.top_k stability.
    if (d < bd[S - 1]) {
      bd[S - 1] = d;
      bi[S - 1] = i;
      // single bubble pass (array was sorted except last slot); strict <
      // keeps equal-distance lower-index entries first.
#pragma unroll
      for (int j = S - 1; j > 0; --j) {
        if (bd[j] < bd[j - 1]) {
          float td = bd[j]; bd[j] = bd[j - 1]; bd[j - 1] = td;
          int ti = bi[j]; bi[j] = bi[j - 1]; bi[j - 1] = ti;
        }
      }
    }
  }

  int* op = nn_idx + ((size_t)b * N2 + q) * S;
#pragma unroll
  for (int j = 0; j < S; ++j) op[j] = bi[j];
}

// ---------------------------------------------------------------------------
// Kernel 2: fused gather + kernel-point weights + wf + conv + relu + concat.
// Block = 256 threads = 32 queries x 8 f-groups. Loop over k (15 kernel pts):
//   phase B: wf_k[q][c] = sum_s w[q][s][k] * feat1[idx[q][s]][c]   (LDS)
//   phase C: acc[q][f] += sum_c wf_k[q][c] * W[k][c][f]            (regs)
// W rows are read broadcast-style from L2 (1 MB, resident); feat1 rows hit L2.
// ---------------------------------------------------------------------------
__global__ __launch_bounds__(256) void conv_kernel(
    const float* __restrict__ xyz1, const float* __restrict__ feat1,
    const float* __restrict__ xyz2, const float* __restrict__ feat2,
    const float* __restrict__ kp, const float* __restrict__ Wmat,
    const int* __restrict__ nn_idx, float* __restrict__ out) {
  __shared__ float s_w[Q][S * K + 1];   // stride 241 (17 mod 32) -> no bank alias over q
  __shared__ float s_wf[Q][C1 + 4];     // stride 132: 16B-aligned rows, banks distinct over q
  __shared__ int s_idx[Q][S];
  __shared__ float s_kp[K * 3];

  const int b = blockIdx.y;
  const int q0 = blockIdx.x * Q;
  const int tid = threadIdx.x;

  if (tid < K * 3) s_kp[tid] = kp[tid];
  for (int t = tid; t < Q * S; t += 256)
    s_idx[t / S][t % S] = nn_idx[((size_t)b * N2 + q0) * S + t];
  __syncthreads();

  // Phase A: kernel-point influence weights w[q][s][k]
  for (int t = tid; t < Q * S * K; t += 256) {
    int q = t / (S * K);
    int r = t - q * (S * K);
    int s = r / K;
    int k = r - s * K;
    int i = s_idx[q][s];
    const float* pn = xyz1 + ((size_t)b * N1 + i) * 3;
    const float* pq = xyz2 + ((size_t)b * N2 + q0 + q) * 3;
    float rx = (pn[0] - pq[0]) - s_kp[k * 3 + 0];
    float ry = (pn[1] - pq[1]) - s_kp[k * 3 + 1];
    float rz = (pn[2] - pq[2]) - s_kp[k * 3 + 2];
    float sq = rx * rx + ry * ry + rz * rz;
    float dist = sqrtf(fmaxf(sq, 1e-12f));
    s_w[q][s * K + k] = fmaxf(0.0f, 1.0f - dist / 0.2f);
  }

  const int q = tid >> 3;   // 0..31
  const int fg = tid & 7;   // 0..7 -> f-chunks at float4 index fg + 8*j
  float4 acc[4];
#pragma unroll
  for (int j = 0; j < 4; ++j) acc[j] = make_float4(0.f, 0.f, 0.f, 0.f);

  for (int k = 0; k < K; ++k) {
    __syncthreads();   // protect s_wf reuse across k iterations (and phase A on k=0)

    // Phase B: wf_k[q][c]
    float4 wf[4];
#pragma unroll
    for (int j = 0; j < 4; ++j) wf[j] = make_float4(0.f, 0.f, 0.f, 0.f);
    for (int s = 0; s < S; ++s) {
      float ws = s_w[q][s * K + k];
      const float4* fp =
          (const float4*)(feat1 + ((size_t)b * N1 + s_idx[q][s]) * C1);
#pragma unroll
      for (int j = 0; j < 4; ++j) {
        float4 f4 = fp[fg + 8 * j];
        wf[j].x += ws * f4.x;
        wf[j].y += ws * f4.y;
        wf[j].z += ws * f4.z;
        wf[j].w += ws * f4.w;
      }
    }
    float4* wrow = (float4*)(&s_wf[q][0]);
#pragma unroll
    for (int j = 0; j < 4; ++j) wrow[fg + 8 * j] = wf[j];
    __syncthreads();

    // Phase C: acc[q][f] += wf_k[q][c] * W[k][c][f]
    const float4* Wk = (const float4*)(Wmat + (size_t)k * C1 * F);
#pragma unroll 4
    for (int c = 0; c < C1; ++c) {
      float wq = s_wf[q][c];
      const float4* Wr = Wk + c * (F / 4);
#pragma unroll
      for (int j = 0; j < 4; ++j) {
        float4 w4 = Wr[fg + 8 * j];
        acc[j].x += wq * w4.x;
        acc[j].y += wq * w4.y;
        acc[j].z += wq * w4.z;
        acc[j].w += wq * w4.w;
      }
    }
  }

  // Epilogue: relu + write conv features (row stride F + C2 = 192)
  float* orow = out + ((size_t)b * N2 + q0 + q) * (F + C2);
#pragma unroll
  for (int j = 0; j < 4; ++j) {
    float4 v;
    v.x = fmaxf(acc[j].x, 0.f);
    v.y = fmaxf(acc[j].y, 0.f);
    v.z = fmaxf(acc[j].z, 0.f);
    v.w = fmaxf(acc[j].w, 0.f);
    ((float4*)orow)[fg + 8 * j] = v;
  }

  // Concat skip features2 into out[..., F:F+C2]
  for (int t = tid; t < Q * (C2 / 4); t += 256) {
    int qq = t / (C2 / 4);
    int j = t - qq * (C2 / 4);
    float4 v = ((const float4*)(feat2 + ((size_t)b * N2 + q0 + qq) * C2))[j];
    ((float4*)(out + ((size_t)b * N2 + q0 + qq) * (F + C2) + F))[j] = v;
  }
}

extern "C" void kernel_launch(void* const* d_in, const int* in_sizes, int n_in,
                              void* d_out, int out_size, void* d_ws, size_t ws_size,
                              hipStream_t stream) {
  const float* xyz1 = (const float*)d_in[0];
  const float* feat1 = (const float*)d_in[1];
  const float* xyz2 = (const float*)d_in[2];
  const float* feat2 = (const float*)d_in[3];
  const float* kp = (const float*)d_in[4];
  const float* Wm = (const float*)d_in[5];
  float* out = (float*)d_out;
  int* nn_idx = (int*)d_ws;  // B*N2*S ints = 2 MB

  knn_kernel<<<dim3(N2 / 256, B), 256, 0, stream>>>(xyz1, xyz2, nn_idx);
  conv_kernel<<<dim3(N2 / Q, B), 256, 0, stream>>>(xyz1, feat1, xyz2, feat2,
                                                   kp, Wm, nn_idx, out);
}

// Round 6
// 1391.070 us; speedup vs baseline: 1.3650x; 1.3650x over previous
//
#include <hip/hip_runtime.h>

#define B 4
#define N1 2048
#define N2 8192
#define C1 128
#define C2 64
#define K 15
#define F 128
#define S 16

// ---------------------------------------------------------------------------
// kNN: R1/R5-VERBATIM per-thread scan (validated selector). Only packaging
// changed: 64-thread blocks x 512 so all 256 CUs get work (R1 used 128
// blocks -> half the chip idle). Per-thread instruction stream identical.
// ---------------------------------------------------------------------------
__global__ __launch_bounds__(64) void knn_kernel(
    const float* __restrict__ xyz1, const float* __restrict__ xyz2,
    unsigned short* __restrict__ nn_idx) {
#pragma clang fp contract(off)
  __shared__ float sx[N1], sy[N1], sz[N1];
  const int b = blockIdx.y;
  const float* p1 = xyz1 + (size_t)b * N1 * 3;
  for (int i = threadIdx.x; i < N1; i += 64) {
    sx[i] = p1[i * 3 + 0];
    sy[i] = p1[i * 3 + 1];
    sz[i] = p1[i * 3 + 2];
  }
  __syncthreads();

  const int q = blockIdx.x * 64 + threadIdx.x;
  const float* p2 = xyz2 + ((size_t)b * N2 + q) * 3;
  const float qx = p2[0], qy = p2[1], qz = p2[2];

  float bd[S];
  int bi[S];
#pragma unroll
  for (int j = 0; j < S; ++j) { bd[j] = 3.4e38f; bi[j] = 0; }

#pragma unroll 4
  for (int i = 0; i < N1; ++i) {
    float dx = qx - sx[i];
    float dy = qy - sy[i];
    float dz = qz - sz[i];
    float d = dx * dx;
    d = d + dy * dy;
    d = d + dz * dz;
    if (d < bd[S - 1]) {   // strict <: incumbent (lower index) wins ties
      bd[S - 1] = d;
      bi[S - 1] = i;
#pragma unroll
      for (int j = S - 1; j > 0; --j) {
        if (bd[j] < bd[j - 1]) {
          float td = bd[j]; bd[j] = bd[j - 1]; bd[j - 1] = td;
          int ti = bi[j]; bi[j] = bi[j - 1]; bi[j - 1] = ti;
        }
      }
    }
  }

  unsigned short* op = nn_idx + ((size_t)b * N2 + q) * S;
#pragma unroll
  for (int j = 0; j < S; ++j) op[j] = (unsigned short)bi[j];
}

// ---------------------------------------------------------------------------
// Conv bisect build: R4's phases A0/A1/B kept EXACTLY; MFMA phase replaced
// with fp32 VALU phase C in R1's proven accumulation order (k outer, c asc).
// 16 q/block, 256 threads. No bf16 anywhere, W read directly (L1 broadcast
// across the 16 q-threads sharing each W word).
// ---------------------------------------------------------------------------
__global__ __launch_bounds__(256) void conv_kernel(
    const float* __restrict__ xyz1, const float* __restrict__ feat1,
    const float* __restrict__ xyz2, const float* __restrict__ feat2,
    const float* __restrict__ kp, const float* __restrict__ W,
    const unsigned short* __restrict__ nn_idx, float* __restrict__ out) {
  __shared__ int s_idx[16][S];
  __shared__ float s_rel[16][S][3];
  __shared__ float s_w[16][260];
  __shared__ float s_wf[16][132];
  __shared__ float s_kp[K * 3];

  const int b = blockIdx.y;
  const int q0 = blockIdx.x * 16;
  const int tid = threadIdx.x;

  if (tid < K * 3) s_kp[tid] = kp[tid];
  s_idx[tid >> 4][tid & 15] = (int)nn_idx[((size_t)b * N2 + q0) * S + tid];
  __syncthreads();

  // Phase A0: rel = neigh_xyz - query (unchanged from R4)
  {
    int q = tid >> 4, s = tid & 15;
    int i = s_idx[q][s];
    const float* pn = xyz1 + ((size_t)b * N1 + i) * 3;
    const float* pq = xyz2 + ((size_t)b * N2 + q0 + q) * 3;
    s_rel[q][s][0] = pn[0] - pq[0];
    s_rel[q][s][1] = pn[1] - pq[1];
    s_rel[q][s][2] = pn[2] - pq[2];
  }
  __syncthreads();

  // Phase A1: kernel-point weights (unchanged from R4)
  for (int t = tid; t < 16 * S * K; t += 256) {
    int q = t / (S * K);
    int r = t - q * (S * K);
    int s = r / K;
    int k = r - s * K;
    float rx = s_rel[q][s][0] - s_kp[k * 3 + 0];
    float ry = s_rel[q][s][1] - s_kp[k * 3 + 1];
    float rz = s_rel[q][s][2] - s_kp[k * 3 + 2];
    float d = sqrtf(fmaxf(rx * rx + ry * ry + rz * rz, 1e-12f));
    s_w[q][s * 16 + k] = fmaxf(0.0f, 1.0f - d / 0.2f);
  }
  __syncthreads();

  const int q = tid & 15;
  const int cg = tid >> 4;

  // Phase B: wfr[k][c in cg*8..+8], feat1 rows read once (unchanged from R4)
  float wfr[K][8];
#pragma unroll
  for (int k = 0; k < K; ++k)
#pragma unroll
    for (int j = 0; j < 8; ++j) wfr[k][j] = 0.0f;

  for (int s = 0; s < S; ++s) {
    int i = s_idx[q][s];
    const float4* fp = (const float4*)(feat1 + ((size_t)b * N1 + i) * C1) + cg * 2;
    float4 n0 = fp[0];
    float4 n1 = fp[1];
    const float4* wr = (const float4*)(&s_w[q][s * 16]);
    float4 w0 = wr[0], w1 = wr[1], w2 = wr[2], w3 = wr[3];
    float wk[16] = {w0.x, w0.y, w0.z, w0.w, w1.x, w1.y, w1.z, w1.w,
                    w2.x, w2.y, w2.z, w2.w, w3.x, w3.y, w3.z, w3.w};
#pragma unroll
    for (int k = 0; k < K; ++k) {
      float w = wk[k];
      wfr[k][0] += w * n0.x;
      wfr[k][1] += w * n0.y;
      wfr[k][2] += w * n0.z;
      wfr[k][3] += w * n0.w;
      wfr[k][4] += w * n1.x;
      wfr[k][5] += w * n1.y;
      wfr[k][6] += w * n1.z;
      wfr[k][7] += w * n1.w;
    }
  }

  // Phase C (VALU, fp32): per k, stage wf_k in LDS, remap to (q2, f-octet),
  // acc[q2][f] += sum_c wf_k[c] * W[k][c][f].  k outer, c ascending = R1.
  const int q2 = tid & 15;
  const int fg = tid >> 4;   // f = fg*8 .. fg*8+7
  float4 acc0 = make_float4(0.f, 0.f, 0.f, 0.f);
  float4 acc1 = make_float4(0.f, 0.f, 0.f, 0.f);

  for (int k = 0; k < K; ++k) {
    __syncthreads();   // protect s_wf reuse across k (phase B regs on k=0)
    *(float4*)(&s_wf[q][cg * 8 + 0]) =
        make_float4(wfr[k][0], wfr[k][1], wfr[k][2], wfr[k][3]);
    *(float4*)(&s_wf[q][cg * 8 + 4]) =
        make_float4(wfr[k][4], wfr[k][5], wfr[k][6], wfr[k][7]);
    __syncthreads();

    const float4* Wk = (const float4*)(W + (size_t)k * C1 * F) + fg * 2;
#pragma unroll 4
    for (int c = 0; c < C1; ++c) {
      float wq = s_wf[q2][c];
      float4 wa = Wk[c * (F / 4)];
      float4 wb = Wk[c * (F / 4) + 1];
      acc0.x += wq * wa.x;
      acc0.y += wq * wa.y;
      acc0.z += wq * wa.z;
      acc0.w += wq * wa.w;
      acc1.x += wq * wb.x;
      acc1.y += wq * wb.y;
      acc1.z += wq * wb.z;
      acc1.w += wq * wb.w;
    }
  }

  // Epilogue: relu + store conv part (row stride F + C2 = 192)
  float* orow = out + ((size_t)b * N2 + q0 + q2) * (F + C2);
  float4 v0, v1;
  v0.x = fmaxf(acc0.x, 0.f); v0.y = fmaxf(acc0.y, 0.f);
  v0.z = fmaxf(acc0.z, 0.f); v0.w = fmaxf(acc0.w, 0.f);
  v1.x = fmaxf(acc1.x, 0.f); v1.y = fmaxf(acc1.y, 0.f);
  v1.z = fmaxf(acc1.z, 0.f); v1.w = fmaxf(acc1.w, 0.f);
  ((float4*)orow)[fg * 2 + 0] = v0;
  ((float4*)orow)[fg * 2 + 1] = v1;

  // Concat skip features2 -> out[..., F:F+C2]
  {
    int qq = tid >> 4;
    int j = tid & 15;
    float4 v = ((const float4*)(feat2 + ((size_t)b * N2 + q0 + qq) * C2))[j];
    ((float4*)(out + ((size_t)b * N2 + q0 + qq) * (F + C2) + F))[j] = v;
  }
}

extern "C" void kernel_launch(void* const* d_in, const int* in_sizes, int n_in,
                              void* d_out, int out_size, void* d_ws, size_t ws_size,
                              hipStream_t stream) {
  const float* xyz1 = (const float*)d_in[0];
  const float* feat1 = (const float*)d_in[1];
  const float* xyz2 = (const float*)d_in[2];
  const float* feat2 = (const float*)d_in[3];
  const float* kp = (const float*)d_in[4];
  const float* Wm = (const float*)d_in[5];
  float* out = (float*)d_out;

  unsigned short* nn_idx = (unsigned short*)d_ws;   // 1 MB, within budget

  knn_kernel<<<dim3(N2 / 64, B), 64, 0, stream>>>(xyz1, xyz2, nn_idx);
  conv_kernel<<<dim3(N2 / 16, B), 256, 0, stream>>>(xyz1, feat1, xyz2, feat2,
                                                    kp, Wm, nn_idx, out);
}

// Round 7
// 752.874 us; speedup vs baseline: 2.5221x; 1.8477x over previous
//
#include <hip/hip_runtime.h>

#define B 4
#define N1 2048
#define N2 8192
#define C1 128
#define C2 64
#define K 15
#define F 128
#define S 16

// ---------------------------------------------------------------------------
// kNN: R6-VERBATIM (proven). One thread per query, sequential scan.
// ---------------------------------------------------------------------------
__global__ __launch_bounds__(64) void knn_kernel(
    const float* __restrict__ xyz1, const float* __restrict__ xyz2,
    unsigned short* __restrict__ nn_idx) {
#pragma clang fp contract(off)
  __shared__ float sx[N1], sy[N1], sz[N1];
  const int b = blockIdx.y;
  const float* p1 = xyz1 + (size_t)b * N1 * 3;
  for (int i = threadIdx.x; i < N1; i += 64) {
    sx[i] = p1[i * 3 + 0];
    sy[i] = p1[i * 3 + 1];
    sz[i] = p1[i * 3 + 2];
  }
  __syncthreads();

  const int q = blockIdx.x * 64 + threadIdx.x;
  const float* p2 = xyz2 + ((size_t)b * N2 + q) * 3;
  const float qx = p2[0], qy = p2[1], qz = p2[2];

  float bd[S];
  int bi[S];
#pragma unroll
  for (int j = 0; j < S; ++j) { bd[j] = 3.4e38f; bi[j] = 0; }

#pragma unroll 4
  for (int i = 0; i < N1; ++i) {
    float dx = qx - sx[i];
    float dy = qy - sy[i];
    float dz = qz - sz[i];
    float d = dx * dx;
    d = d + dy * dy;
    d = d + dz * dz;
    if (d < bd[S - 1]) {
      bd[S - 1] = d;
      bi[S - 1] = i;
#pragma unroll
      for (int j = S - 1; j > 0; --j) {
        if (bd[j] < bd[j - 1]) {
          float td = bd[j]; bd[j] = bd[j - 1]; bd[j - 1] = td;
          int ti = bi[j]; bi[j] = bi[j - 1]; bi[j - 1] = ti;
        }
      }
    }
  }

  unsigned short* op = nn_idx + ((size_t)b * N2 + q) * S;
#pragma unroll
  for (int j = 0; j < S; ++j) op[j] = (unsigned short)bi[j];
}

// ---------------------------------------------------------------------------
// Conv: phases A0/A1/B verbatim from R6 (proven). Phase C register-tiled:
// thread = (qg x 8q, cs c-quarter, fg x 4f); per c: 2 LDS b128 (broadcast)
// + 1 coalesced W float4 + 32 FMA. Cross-quarter reduce in s_red.
// ---------------------------------------------------------------------------
__global__ __launch_bounds__(256) void conv_kernel(
    const float* __restrict__ xyz1, const float* __restrict__ feat1,
    const float* __restrict__ xyz2, const float* __restrict__ feat2,
    const float* __restrict__ kp, const float* __restrict__ W,
    const unsigned short* __restrict__ nn_idx, float* __restrict__ out) {
  __shared__ int s_idx[16][S];
  __shared__ float s_rel[16][S][3];
  __shared__ float s_w[16][260];
  __shared__ float s_wf[C1][20];       // [c][q], row 20 -> 16B-aligned q-reads
  __shared__ float s_red[4][16][132];  // cs partials
  __shared__ float s_kp[K * 3];

  const int b = blockIdx.y;
  const int q0 = blockIdx.x * 16;
  const int tid = threadIdx.x;

  if (tid < K * 3) s_kp[tid] = kp[tid];
  s_idx[tid >> 4][tid & 15] = (int)nn_idx[((size_t)b * N2 + q0) * S + tid];
  __syncthreads();

  // Phase A0 (R6-verbatim)
  {
    int q = tid >> 4, s = tid & 15;
    int i = s_idx[q][s];
    const float* pn = xyz1 + ((size_t)b * N1 + i) * 3;
    const float* pq = xyz2 + ((size_t)b * N2 + q0 + q) * 3;
    s_rel[q][s][0] = pn[0] - pq[0];
    s_rel[q][s][1] = pn[1] - pq[1];
    s_rel[q][s][2] = pn[2] - pq[2];
  }
  __syncthreads();

  // Phase A1 (R6-verbatim)
  for (int t = tid; t < 16 * S * K; t += 256) {
    int q = t / (S * K);
    int r = t - q * (S * K);
    int s = r / K;
    int k = r - s * K;
    float rx = s_rel[q][s][0] - s_kp[k * 3 + 0];
    float ry = s_rel[q][s][1] - s_kp[k * 3 + 1];
    float rz = s_rel[q][s][2] - s_kp[k * 3 + 2];
    float d = sqrtf(fmaxf(rx * rx + ry * ry + rz * rz, 1e-12f));
    s_w[q][s * 16 + k] = fmaxf(0.0f, 1.0f - d / 0.2f);
  }
  __syncthreads();

  const int q = tid & 15;
  const int cg = tid >> 4;

  // Phase B (R6-verbatim): wfr[k][c in cg*8..+8]
  float wfr[K][8];
#pragma unroll
  for (int k = 0; k < K; ++k)
#pragma unroll
    for (int j = 0; j < 8; ++j) wfr[k][j] = 0.0f;

  for (int s = 0; s < S; ++s) {
    int i = s_idx[q][s];
    const float4* fp = (const float4*)(feat1 + ((size_t)b * N1 + i) * C1) + cg * 2;
    float4 n0 = fp[0];
    float4 n1 = fp[1];
    const float4* wr = (const float4*)(&s_w[q][s * 16]);
    float4 w0 = wr[0], w1 = wr[1], w2 = wr[2], w3 = wr[3];
    float wk[16] = {w0.x, w0.y, w0.z, w0.w, w1.x, w1.y, w1.z, w1.w,
                    w2.x, w2.y, w2.z, w2.w, w3.x, w3.y, w3.z, w3.w};
#pragma unroll
    for (int k = 0; k < K; ++k) {
      float w = wk[k];
      wfr[k][0] += w * n0.x;
      wfr[k][1] += w * n0.y;
      wfr[k][2] += w * n0.z;
      wfr[k][3] += w * n0.w;
      wfr[k][4] += w * n1.x;
      wfr[k][5] += w * n1.y;
      wfr[k][6] += w * n1.z;
      wfr[k][7] += w * n1.w;
    }
  }

  // Phase C: register-tiled GEMM. Thread roles:
  const int qg = tid >> 7;          // 0..1 -> q = qg*8 + qi (qi 0..7)
  const int cs = (tid >> 5) & 3;    // c-quarter: c = cs*32 + c2
  const int fg = tid & 31;          // f = fg*4 .. fg*4+3
  float4 acc[8];
#pragma unroll
  for (int qi = 0; qi < 8; ++qi) acc[qi] = make_float4(0.f, 0.f, 0.f, 0.f);

  for (int k = 0; k < K; ++k) {
    __syncthreads();   // s_wf reuse guard
    // stage wf_k transposed: (q=tid&15, cg=tid>>4) writes 8 scalars
#pragma unroll
    for (int j = 0; j < 8; ++j) s_wf[cg * 8 + j][q] = wfr[k][j];
    __syncthreads();

    const float4* Wk4 = (const float4*)(W + (size_t)k * C1 * F) + fg;
#pragma unroll 4
    for (int c2 = 0; c2 < 32; ++c2) {
      int c = cs * 32 + c2;
      float4 wa = *(const float4*)(&s_wf[c][qg * 8 + 0]);  // q qg*8..+3
      float4 wb = *(const float4*)(&s_wf[c][qg * 8 + 4]);  // q qg*8+4..+7
      float4 w4 = Wk4[c * 32];                             // W[k][c][fg*4..+3]
      acc[0].x += wa.x * w4.x; acc[0].y += wa.x * w4.y;
      acc[0].z += wa.x * w4.z; acc[0].w += wa.x * w4.w;
      acc[1].x += wa.y * w4.x; acc[1].y += wa.y * w4.y;
      acc[1].z += wa.y * w4.z; acc[1].w += wa.y * w4.w;
      acc[2].x += wa.z * w4.x; acc[2].y += wa.z * w4.y;
      acc[2].z += wa.z * w4.z; acc[2].w += wa.z * w4.w;
      acc[3].x += wa.w * w4.x; acc[3].y += wa.w * w4.y;
      acc[3].z += wa.w * w4.z; acc[3].w += wa.w * w4.w;
      acc[4].x += wb.x * w4.x; acc[4].y += wb.x * w4.y;
      acc[4].z += wb.x * w4.z; acc[4].w += wb.x * w4.w;
      acc[5].x += wb.y * w4.x; acc[5].y += wb.y * w4.y;
      acc[5].z += wb.y * w4.z; acc[5].w += wb.y * w4.w;
      acc[6].x += wb.z * w4.x; acc[6].y += wb.z * w4.y;
      acc[6].z += wb.z * w4.z; acc[6].w += wb.z * w4.w;
      acc[7].x += wb.w * w4.x; acc[7].y += wb.w * w4.y;
      acc[7].z += wb.w * w4.z; acc[7].w += wb.w * w4.w;
    }
  }

  // Store cs-partials, reduce across quarters, relu, write.
#pragma unroll
  for (int qi = 0; qi < 8; ++qi)
    *(float4*)(&s_red[cs][qg * 8 + qi][fg * 4]) = acc[qi];
  __syncthreads();

  for (int t = tid; t < 512; t += 256) {   // 512 float4 = 16q x 128f
    int qq = t >> 5;
    int fj = t & 31;
    float4 a0 = *(const float4*)&s_red[0][qq][fj * 4];
    float4 a1 = *(const float4*)&s_red[1][qq][fj * 4];
    float4 a2 = *(const float4*)&s_red[2][qq][fj * 4];
    float4 a3 = *(const float4*)&s_red[3][qq][fj * 4];
    float4 v;
    v.x = fmaxf(a0.x + a1.x + a2.x + a3.x, 0.0f);
    v.y = fmaxf(a0.y + a1.y + a2.y + a3.y, 0.0f);
    v.z = fmaxf(a0.z + a1.z + a2.z + a3.z, 0.0f);
    v.w = fmaxf(a0.w + a1.w + a2.w + a3.w, 0.0f);
    ((float4*)(out + ((size_t)b * N2 + q0 + qq) * (F + C2)))[fj] = v;
  }

  // Concat skip features2
  {
    int qq = tid >> 4;
    int j = tid & 15;
    float4 v = ((const float4*)(feat2 + ((size_t)b * N2 + q0 + qq) * C2))[j];
    ((float4*)(out + ((size_t)b * N2 + q0 + qq) * (F + C2) + F))[j] = v;
  }
}

extern "C" void kernel_launch(void* const* d_in, const int* in_sizes, int n_in,
                              void* d_out, int out_size, void* d_ws, size_t ws_size,
                              hipStream_t stream) {
  const float* xyz1 = (const float*)d_in[0];
  const float* feat1 = (const float*)d_in[1];
  const float* xyz2 = (const float*)d_in[2];
  const float* feat2 = (const float*)d_in[3];
  const float* kp = (const float*)d_in[4];
  const float* Wm = (const float*)d_in[5];
  float* out = (float*)d_out;

  unsigned short* nn_idx = (unsigned short*)d_ws;   // 1 MB

  knn_kernel<<<dim3(N2 / 64, B), 64, 0, stream>>>(xyz1, xyz2, nn_idx);
  conv_kernel<<<dim3(N2 / 16, B), 256, 0, stream>>>(xyz1, feat1, xyz2, feat2,
                                                    kp, Wm, nn_idx, out);
}

// Round 8
// 588.252 us; speedup vs baseline: 3.2279x; 1.2799x over previous
//
#include <hip/hip_runtime.h>

#define B 4
#define N1 2048
#define N2 8192
#define C1 128
#define C2 64
#define K 15
#define F 128
#define S 16

// ---------------------------------------------------------------------------
// kNN: 512 threads = 64 queries x 8 chunk-waves. Wave wv scans
// xyz1[wv*256 .. +256) with per-lane top-16 (ascending, strict < => lowest
// index wins ties, identical to R6's sequential semantics). 64-thread
// chunk-major merge with lexicographic (d, idx) tie-break.
// Distance math byte-identical to R6 (contract off, numpy order).
// ---------------------------------------------------------------------------
__global__ __launch_bounds__(512) void knn_kernel(
    const float* __restrict__ xyz1, const float* __restrict__ xyz2,
    unsigned short* __restrict__ nn_idx) {
#pragma clang fp contract(off)
  __shared__ float sx[N1], sy[N1], sz[N1];          // 24 KB
  __shared__ float s_cd[64][130];                   // 32.5 KB, stride 130 -> 2-way
  __shared__ unsigned short s_ci[64][130];          // 16.3 KB
  const int b = blockIdx.y;
  const int q0 = blockIdx.x * 64;
  const int tid = threadIdx.x;

  const float* p1 = xyz1 + (size_t)b * N1 * 3;
  for (int i = tid; i < N1; i += 512) {
    sx[i] = p1[i * 3 + 0];
    sy[i] = p1[i * 3 + 1];
    sz[i] = p1[i * 3 + 2];
  }
  __syncthreads();

  const int wv = tid >> 6;
  const int lane = tid & 63;
  const float* p2 = xyz2 + ((size_t)b * N2 + q0 + lane) * 3;
  const float qx = p2[0], qy = p2[1], qz = p2[2];

  float bd[S];
  int bi[S];
#pragma unroll
  for (int j = 0; j < S; ++j) { bd[j] = 3.4e38f; bi[j] = 0x7fffffff; }

  const int i0 = wv * 256;
#pragma unroll 4
  for (int ii = 0; ii < 256; ++ii) {
    const int i = i0 + ii;
    float dx = qx - sx[i];
    float dy = qy - sy[i];
    float dz = qz - sz[i];
    float d = dx * dx;
    d = d + dy * dy;
    d = d + dz * dz;
    if (d < bd[S - 1]) {   // ascending scan: strict < == lex (d, idx)
      bd[S - 1] = d;
      bi[S - 1] = i;
#pragma unroll
      for (int j = S - 1; j > 0; --j) {
        if (bd[j] < bd[j - 1]) {
          float td = bd[j]; bd[j] = bd[j - 1]; bd[j - 1] = td;
          int ti = bi[j]; bi[j] = bi[j - 1]; bi[j - 1] = ti;
        }
      }
    }
  }
#pragma unroll
  for (int j = 0; j < S; ++j) {
    s_cd[lane][wv * 16 + j] = bd[j];
    s_ci[lane][wv * 16 + j] = (unsigned short)bi[j];
  }
  __syncthreads();

  if (tid < 64) {
    float md[S];
    int mi[S];
#pragma unroll
    for (int j = 0; j < S; ++j) { md[j] = 3.4e38f; mi[j] = 0x7fffffff; }
    for (int j = 0; j < 128; ++j) {   // chunk-major; lex (d, idx) tie-break
      float d = s_cd[tid][j];
      int i = (int)s_ci[tid][j];
      if (d < md[S - 1] || (d == md[S - 1] && i < mi[S - 1])) {
        md[S - 1] = d;
        mi[S - 1] = i;
#pragma unroll
        for (int j2 = S - 1; j2 > 0; --j2) {
          if (md[j2] < md[j2 - 1] ||
              (md[j2] == md[j2 - 1] && mi[j2] < mi[j2 - 1])) {
            float td = md[j2]; md[j2] = md[j2 - 1]; md[j2 - 1] = td;
            int ti = mi[j2]; mi[j2] = mi[j2 - 1]; mi[j2 - 1] = ti;
          }
        }
      }
    }
    unsigned short* op = nn_idx + ((size_t)b * N2 + q0 + tid) * S;
#pragma unroll
    for (int j = 0; j < S; ++j) op[j] = (unsigned short)mi[j];
  }
}

// ---------------------------------------------------------------------------
// Conv: R7-VERBATIM (proven: pass @ 0.03125). Phases A0/A1/B + register-tiled
// phase C + cross-quarter LDS reduce + concat.
// ---------------------------------------------------------------------------
__global__ __launch_bounds__(256) void conv_kernel(
    const float* __restrict__ xyz1, const float* __restrict__ feat1,
    const float* __restrict__ xyz2, const float* __restrict__ feat2,
    const float* __restrict__ kp, const float* __restrict__ W,
    const unsigned short* __restrict__ nn_idx, float* __restrict__ out) {
  __shared__ int s_idx[16][S];
  __shared__ float s_rel[16][S][3];
  __shared__ float s_w[16][260];
  __shared__ float s_wf[C1][20];
  __shared__ float s_red[4][16][132];
  __shared__ float s_kp[K * 3];

  const int b = blockIdx.y;
  const int q0 = blockIdx.x * 16;
  const int tid = threadIdx.x;

  if (tid < K * 3) s_kp[tid] = kp[tid];
  s_idx[tid >> 4][tid & 15] = (int)nn_idx[((size_t)b * N2 + q0) * S + tid];
  __syncthreads();

  {
    int q = tid >> 4, s = tid & 15;
    int i = s_idx[q][s];
    const float* pn = xyz1 + ((size_t)b * N1 + i) * 3;
    const float* pq = xyz2 + ((size_t)b * N2 + q0 + q) * 3;
    s_rel[q][s][0] = pn[0] - pq[0];
    s_rel[q][s][1] = pn[1] - pq[1];
    s_rel[q][s][2] = pn[2] - pq[2];
  }
  __syncthreads();

  for (int t = tid; t < 16 * S * K; t += 256) {
    int q = t / (S * K);
    int r = t - q * (S * K);
    int s = r / K;
    int k = r - s * K;
    float rx = s_rel[q][s][0] - s_kp[k * 3 + 0];
    float ry = s_rel[q][s][1] - s_kp[k * 3 + 1];
    float rz = s_rel[q][s][2] - s_kp[k * 3 + 2];
    float d = sqrtf(fmaxf(rx * rx + ry * ry + rz * rz, 1e-12f));
    s_w[q][s * 16 + k] = fmaxf(0.0f, 1.0f - d / 0.2f);
  }
  __syncthreads();

  const int q = tid & 15;
  const int cg = tid >> 4;

  float wfr[K][8];
#pragma unroll
  for (int k = 0; k < K; ++k)
#pragma unroll
    for (int j = 0; j < 8; ++j) wfr[k][j] = 0.0f;

  for (int s = 0; s < S; ++s) {
    int i = s_idx[q][s];
    const float4* fp = (const float4*)(feat1 + ((size_t)b * N1 + i) * C1) + cg * 2;
    float4 n0 = fp[0];
    float4 n1 = fp[1];
    const float4* wr = (const float4*)(&s_w[q][s * 16]);
    float4 w0 = wr[0], w1 = wr[1], w2 = wr[2], w3 = wr[3];
    float wk[16] = {w0.x, w0.y, w0.z, w0.w, w1.x, w1.y, w1.z, w1.w,
                    w2.x, w2.y, w2.z, w2.w, w3.x, w3.y, w3.z, w3.w};
#pragma unroll
    for (int k = 0; k < K; ++k) {
      float w = wk[k];
      wfr[k][0] += w * n0.x;
      wfr[k][1] += w * n0.y;
      wfr[k][2] += w * n0.z;
      wfr[k][3] += w * n0.w;
      wfr[k][4] += w * n1.x;
      wfr[k][5] += w * n1.y;
      wfr[k][6] += w * n1.z;
      wfr[k][7] += w * n1.w;
    }
  }

  const int qg = tid >> 7;
  const int cs = (tid >> 5) & 3;
  const int fg = tid & 31;
  float4 acc[8];
#pragma unroll
  for (int qi = 0; qi < 8; ++qi) acc[qi] = make_float4(0.f, 0.f, 0.f, 0.f);

  for (int k = 0; k < K; ++k) {
    __syncthreads();
#pragma unroll
    for (int j = 0; j < 8; ++j) s_wf[cg * 8 + j][q] = wfr[k][j];
    __syncthreads();

    const float4* Wk4 = (const float4*)(W + (size_t)k * C1 * F) + fg;
#pragma unroll 4
    for (int c2 = 0; c2 < 32; ++c2) {
      int c = cs * 32 + c2;
      float4 wa = *(const float4*)(&s_wf[c][qg * 8 + 0]);
      float4 wb = *(const float4*)(&s_wf[c][qg * 8 + 4]);
      float4 w4 = Wk4[c * 32];
      acc[0].x += wa.x * w4.x; acc[0].y += wa.x * w4.y;
      acc[0].z += wa.x * w4.z; acc[0].w += wa.x * w4.w;
      acc[1].x += wa.y * w4.x; acc[1].y += wa.y * w4.y;
      acc[1].z += wa.y * w4.z; acc[1].w += wa.y * w4.w;
      acc[2].x += wa.z * w4.x; acc[2].y += wa.z * w4.y;
      acc[2].z += wa.z * w4.z; acc[2].w += wa.z * w4.w;
      acc[3].x += wa.w * w4.x; acc[3].y += wa.w * w4.y;
      acc[3].z += wa.w * w4.z; acc[3].w += wa.w * w4.w;
      acc[4].x += wb.x * w4.x; acc[4].y += wb.x * w4.y;
      acc[4].z += wb.x * w4.z; acc[4].w += wb.x * w4.w;
      acc[5].x += wb.y * w4.x; acc[5].y += wb.y * w4.y;
      acc[5].z += wb.y * w4.z; acc[5].w += wb.y * w4.w;
      acc[6].x += wb.z * w4.x; acc[6].y += wb.z * w4.y;
      acc[6].z += wb.z * w4.z; acc[6].w += wb.z * w4.w;
      acc[7].x += wb.w * w4.x; acc[7].y += wb.w * w4.y;
      acc[7].z += wb.w * w4.z; acc[7].w += wb.w * w4.w;
    }
  }

#pragma unroll
  for (int qi = 0; qi < 8; ++qi)
    *(float4*)(&s_red[cs][qg * 8 + qi][fg * 4]) = acc[qi];
  __syncthreads();

  for (int t = tid; t < 512; t += 256) {
    int qq = t >> 5;
    int fj = t & 31;
    float4 a0 = *(const float4*)&s_red[0][qq][fj * 4];
    float4 a1 = *(const float4*)&s_red[1][qq][fj * 4];
    float4 a2 = *(const float4*)&s_red[2][qq][fj * 4];
    float4 a3 = *(const float4*)&s_red[3][qq][fj * 4];
    float4 v;
    v.x = fmaxf(a0.x + a1.x + a2.x + a3.x, 0.0f);
    v.y = fmaxf(a0.y + a1.y + a2.y + a3.y, 0.0f);
    v.z = fmaxf(a0.z + a1.z + a2.z + a3.z, 0.0f);
    v.w = fmaxf(a0.w + a1.w + a2.w + a3.w, 0.0f);
    ((float4*)(out + ((size_t)b * N2 + q0 + qq) * (F + C2)))[fj] = v;
  }

  {
    int qq = tid >> 4;
    int j = tid & 15;
    float4 v = ((const float4*)(feat2 + ((size_t)b * N2 + q0 + qq) * C2))[j];
    ((float4*)(out + ((size_t)b * N2 + q0 + qq) * (F + C2) + F))[j] = v;
  }
}

extern "C" void kernel_launch(void* const* d_in, const int* in_sizes, int n_in,
                              void* d_out, int out_size, void* d_ws, size_t ws_size,
                              hipStream_t stream) {
  const float* xyz1 = (const float*)d_in[0];
  const float* feat1 = (const float*)d_in[1];
  const float* xyz2 = (const float*)d_in[2];
  const float* feat2 = (const float*)d_in[3];
  const float* kp = (const float*)d_in[4];
  const float* Wm = (const float*)d_in[5];
  float* out = (float*)d_out;

  unsigned short* nn_idx = (unsigned short*)d_ws;   // 1 MB

  knn_kernel<<<dim3(N2 / 64, B), 512, 0, stream>>>(xyz1, xyz2, nn_idx);
  conv_kernel<<<dim3(N2 / 16, B), 256, 0, stream>>>(xyz1, feat1, xyz2, feat2,
                                                    kp, Wm, nn_idx, out);
}

// Round 9
// 543.082 us; speedup vs baseline: 3.4964x; 1.0832x over previous
//
#include <hip/hip_runtime.h>

#define B 4
#define N1 2048
#define N2 8192
#define C1 128
#define C2 64
#define K 15
#define F 128
#define S 16

// ---------------------------------------------------------------------------
// kNN: 512 threads = 16 queries x (8 waves x 4 subchunks) = 32 lists/query.
// Lane (q = lane&15, sub = lane>>4) of wave wv scans strided subchunk
// i = wv*256 + 4*ii + sub, ii=0..63 (ascending within its subset; strict-<
// insert => lex-(d,idx) top-16 of the subset; broadcast LDS reads hit 4
// distinct banks -> conflict-free). 5-round parallel two-pointer tree merge
// with explicit lex compare (R8-validated semantics), reg-buffered and
// barrier-separated so in-place list compaction is race-free.
// ---------------------------------------------------------------------------
__global__ __launch_bounds__(512) void knn_kernel(
    const float* __restrict__ xyz1, const float* __restrict__ xyz2,
    unsigned short* __restrict__ nn_idx) {
#pragma clang fp contract(off)
  __shared__ float sx[N1], sy[N1], sz[N1];     // 24 KB
  __shared__ float s_cd[16][522];              // 33.4 KB (row 522: banks spread)
  __shared__ unsigned short s_ci[16][522];     // 16.7 KB
  const int b = blockIdx.y;
  const int q0 = blockIdx.x * 16;
  const int tid = threadIdx.x;

  const float* p1 = xyz1 + (size_t)b * N1 * 3;
  for (int i = tid; i < N1; i += 512) {
    sx[i] = p1[i * 3 + 0];
    sy[i] = p1[i * 3 + 1];
    sz[i] = p1[i * 3 + 2];
  }
  __syncthreads();

  const int wv = tid >> 6;
  const int lane = tid & 63;
  const int q = lane & 15;
  const int sub = lane >> 4;
  const float* p2 = xyz2 + ((size_t)b * N2 + q0 + q) * 3;
  const float qx = p2[0], qy = p2[1], qz = p2[2];

  float bd[S];
  int bi[S];
#pragma unroll
  for (int j = 0; j < S; ++j) { bd[j] = 3.4e38f; bi[j] = 0x7fffffff; }

  const int i0 = wv * 256 + sub;
  for (int ii = 0; ii < 64; ++ii) {
    const int i = i0 + (ii << 2);
    float dx = qx - sx[i];
    float dy = qy - sy[i];
    float dz = qz - sz[i];
    float d = dx * dx;
    d = d + dy * dy;
    d = d + dz * dz;
    if (d < bd[S - 1]) {   // ascending subset scan: strict < == lex (d, idx)
      bd[S - 1] = d;
      bi[S - 1] = i;
#pragma unroll
      for (int j = S - 1; j > 0; --j) {
        if (bd[j] < bd[j - 1]) {
          float td = bd[j]; bd[j] = bd[j - 1]; bd[j - 1] = td;
          int ti = bi[j]; bi[j] = bi[j - 1]; bi[j - 1] = ti;
        }
      }
    }
  }
  {
    const int ls = (wv * 4 + sub) * 16;
#pragma unroll
    for (int j = 0; j < S; ++j) {
      s_cd[q][ls + j] = bd[j];
      s_ci[q][ls + j] = (unsigned short)bi[j];
    }
  }
  __syncthreads();

  // Tree merge: L lists -> L/2, in-place (slot m), barrier-separated.
  for (int L = 32; L >= 4; L >>= 1) {
    const int half = L >> 1;
    const int nact = 16 * half;
    const int valid = tid < nact;
    float od[16];
    int oi[16];
    int q2 = 0, m = 0;
    if (valid) {
      q2 = tid / half;
      m = tid - q2 * half;
      int pa = (2 * m) * 16, ea = pa + 16;
      int pb = ea, eb = pb + 16;
#pragma unroll
      for (int j = 0; j < 16; ++j) {
        const int a_ok = pa < ea, b_ok = pb < eb;
        const int ra = a_ok ? pa : ea - 1;
        const int rb = b_ok ? pb : eb - 1;
        float da = s_cd[q2][ra];
        int ia = (int)s_ci[q2][ra];
        float db = s_cd[q2][rb];
        int ib = (int)s_ci[q2][rb];
        const int ta = a_ok && (!b_ok || da < db || (da == db && ia < ib));
        od[j] = ta ? da : db;
        oi[j] = ta ? ia : ib;
        pa += ta;
        pb += !ta;
      }
    }
    __syncthreads();
    if (valid) {
#pragma unroll
      for (int j = 0; j < 16; ++j) {
        s_cd[q2][m * 16 + j] = od[j];
        s_ci[q2][m * 16 + j] = (unsigned short)oi[j];
      }
    }
    __syncthreads();
  }

  // Final round: merge lists 0,1 -> global output (16 threads).
  if (tid < 16) {
    const int q2 = tid;
    int pa = 0, ea = 16, pb = 16, eb = 32;
    unsigned short* op = nn_idx + ((size_t)b * N2 + q0 + q2) * S;
#pragma unroll
    for (int j = 0; j < 16; ++j) {
      const int a_ok = pa < ea, b_ok = pb < eb;
      const int ra = a_ok ? pa : ea - 1;
      const int rb = b_ok ? pb : eb - 1;
      float da = s_cd[q2][ra];
      int ia = (int)s_ci[q2][ra];
      float db = s_cd[q2][rb];
      int ib = (int)s_ci[q2][rb];
      const int ta = a_ok && (!b_ok || da < db || (da == db && ia < ib));
      op[j] = (unsigned short)(ta ? ia : ib);
      pa += ta;
      pb += !ta;
    }
  }
}

// ---------------------------------------------------------------------------
// Conv: R8-VERBATIM compute. Only change: s_idx/s_rel/s_w (dead after phase
// B, 15 barriers before s_red's first write) now ALIAS s_red in one buffer.
// LDS 65 -> 44 KB => 3 blocks/CU (12 waves) for latency hiding.
// ---------------------------------------------------------------------------
__global__ __launch_bounds__(256) void conv_kernel(
    const float* __restrict__ xyz1, const float* __restrict__ feat1,
    const float* __restrict__ xyz2, const float* __restrict__ feat2,
    const float* __restrict__ kp, const float* __restrict__ W,
    const unsigned short* __restrict__ nn_idx, float* __restrict__ out) {
  __shared__ __align__(16) float s_buf[8448];   // 33.8 KB, aliased regions:
  int (*s_idx)[S] = (int(*)[S])(s_buf);               // [0, 256)
  float (*s_rel)[S][3] = (float(*)[S][3])(s_buf + 256);  // [256, 1024)
  float (*s_w)[260] = (float(*)[260])(s_buf + 1024);     // [1024, 5184)
  float (*s_red)[16][132] = (float(*)[16][132])(s_buf);  // [0, 8448) alias
  __shared__ float s_wf[C1][20];               // 10 KB (live through k-loop)
  __shared__ float s_kp[K * 3];

  const int b = blockIdx.y;
  const int q0 = blockIdx.x * 16;
  const int tid = threadIdx.x;

  if (tid < K * 3) s_kp[tid] = kp[tid];
  s_idx[tid >> 4][tid & 15] = (int)nn_idx[((size_t)b * N2 + q0) * S + tid];
  __syncthreads();

  {
    int q = tid >> 4, s = tid & 15;
    int i = s_idx[q][s];
    const float* pn = xyz1 + ((size_t)b * N1 + i) * 3;
    const float* pq = xyz2 + ((size_t)b * N2 + q0 + q) * 3;
    s_rel[q][s][0] = pn[0] - pq[0];
    s_rel[q][s][1] = pn[1] - pq[1];
    s_rel[q][s][2] = pn[2] - pq[2];
  }
  __syncthreads();

  for (int t = tid; t < 16 * S * K; t += 256) {
    int q = t / (S * K);
    int r = t - q * (S * K);
    int s = r / K;
    int k = r - s * K;
    float rx = s_rel[q][s][0] - s_kp[k * 3 + 0];
    float ry = s_rel[q][s][1] - s_kp[k * 3 + 1];
    float rz = s_rel[q][s][2] - s_kp[k * 3 + 2];
    float d = sqrtf(fmaxf(rx * rx + ry * ry + rz * rz, 1e-12f));
    s_w[q][s * 16 + k] = fmaxf(0.0f, 1.0f - d / 0.2f);
  }
  __syncthreads();

  const int q = tid & 15;
  const int cg = tid >> 4;

  float wfr[K][8];
#pragma unroll
  for (int k = 0; k < K; ++k)
#pragma unroll
    for (int j = 0; j < 8; ++j) wfr[k][j] = 0.0f;

  for (int s = 0; s < S; ++s) {
    int i = s_idx[q][s];
    const float4* fp = (const float4*)(feat1 + ((size_t)b * N1 + i) * C1) + cg * 2;
    float4 n0 = fp[0];
    float4 n1 = fp[1];
    const float4* wr = (const float4*)(&s_w[q][s * 16]);
    float4 w0 = wr[0], w1 = wr[1], w2 = wr[2], w3 = wr[3];
    float wk[16] = {w0.x, w0.y, w0.z, w0.w, w1.x, w1.y, w1.z, w1.w,
                    w2.x, w2.y, w2.z, w2.w, w3.x, w3.y, w3.z, w3.w};
#pragma unroll
    for (int k = 0; k < K; ++k) {
      float w = wk[k];
      wfr[k][0] += w * n0.x;
      wfr[k][1] += w * n0.y;
      wfr[k][2] += w * n0.z;
      wfr[k][3] += w * n0.w;
      wfr[k][4] += w * n1.x;
      wfr[k][5] += w * n1.y;
      wfr[k][6] += w * n1.z;
      wfr[k][7] += w * n1.w;
    }
  }

  const int qg = tid >> 7;
  const int cs = (tid >> 5) & 3;
  const int fg = tid & 31;
  float4 acc[8];
#pragma unroll
  for (int qi = 0; qi < 8; ++qi) acc[qi] = make_float4(0.f, 0.f, 0.f, 0.f);

  for (int k = 0; k < K; ++k) {
    __syncthreads();
#pragma unroll
    for (int j = 0; j < 8; ++j) s_wf[cg * 8 + j][q] = wfr[k][j];
    __syncthreads();

    const float4* Wk4 = (const float4*)(W + (size_t)k * C1 * F) + fg;
#pragma unroll 4
    for (int c2 = 0; c2 < 32; ++c2) {
      int c = cs * 32 + c2;
      float4 wa = *(const float4*)(&s_wf[c][qg * 8 + 0]);
      float4 wb = *(const float4*)(&s_wf[c][qg * 8 + 4]);
      float4 w4 = Wk4[c * 32];
      acc[0].x += wa.x * w4.x; acc[0].y += wa.x * w4.y;
      acc[0].z += wa.x * w4.z; acc[0].w += wa.x * w4.w;
      acc[1].x += wa.y * w4.x; acc[1].y += wa.y * w4.y;
      acc[1].z += wa.y * w4.z; acc[1].w += wa.y * w4.w;
      acc[2].x += wa.z * w4.x; acc[2].y += wa.z * w4.y;
      acc[2].z += wa.z * w4.z; acc[2].w += wa.z * w4.w;
      acc[3].x += wa.w * w4.x; acc[3].y += wa.w * w4.y;
      acc[3].z += wa.w * w4.z; acc[3].w += wa.w * w4.w;
      acc[4].x += wb.x * w4.x; acc[4].y += wb.x * w4.y;
      acc[4].z += wb.x * w4.z; acc[4].w += wb.x * w4.w;
      acc[5].x += wb.y * w4.x; acc[5].y += wb.y * w4.y;
      acc[5].z += wb.y * w4.z; acc[5].w += wb.y * w4.w;
      acc[6].x += wb.z * w4.x; acc[6].y += wb.z * w4.y;
      acc[6].z += wb.z * w4.z; acc[6].w += wb.z * w4.w;
      acc[7].x += wb.w * w4.x; acc[7].y += wb.w * w4.y;
      acc[7].z += wb.w * w4.z; acc[7].w += wb.w * w4.w;
    }
  }

  // s_red aliases s_idx/s_rel/s_w — all dead since phase B (>=15 barriers).
#pragma unroll
  for (int qi = 0; qi < 8; ++qi)
    *(float4*)(&s_red[cs][qg * 8 + qi][fg * 4]) = acc[qi];
  __syncthreads();

  for (int t = tid; t < 512; t += 256) {
    int qq = t >> 5;
    int fj = t & 31;
    float4 a0 = *(const float4*)&s_red[0][qq][fj * 4];
    float4 a1 = *(const float4*)&s_red[1][qq][fj * 4];
    float4 a2 = *(const float4*)&s_red[2][qq][fj * 4];
    float4 a3 = *(const float4*)&s_red[3][qq][fj * 4];
    float4 v;
    v.x = fmaxf(a0.x + a1.x + a2.x + a3.x, 0.0f);
    v.y = fmaxf(a0.y + a1.y + a2.y + a3.y, 0.0f);
    v.z = fmaxf(a0.z + a1.z + a2.z + a3.z, 0.0f);
    v.w = fmaxf(a0.w + a1.w + a2.w + a3.w, 0.0f);
    ((float4*)(out + ((size_t)b * N2 + q0 + qq) * (F + C2)))[fj] = v;
  }

  {
    int qq = tid >> 4;
    int j = tid & 15;
    float4 v = ((const float4*)(feat2 + ((size_t)b * N2 + q0 + qq) * C2))[j];
    ((float4*)(out + ((size_t)b * N2 + q0 + qq) * (F + C2) + F))[j] = v;
  }
}

extern "C" void kernel_launch(void* const* d_in, const int* in_sizes, int n_in,
                              void* d_out, int out_size, void* d_ws, size_t ws_size,
                              hipStream_t stream) {
  const float* xyz1 = (const float*)d_in[0];
  const float* feat1 = (const float*)d_in[1];
  const float* xyz2 = (const float*)d_in[2];
  const float* feat2 = (const float*)d_in[3];
  const float* kp = (const float*)d_in[4];
  const float* Wm = (const float*)d_in[5];
  float* out = (float*)d_out;

  unsigned short* nn_idx = (unsigned short*)d_ws;   // 1 MB

  knn_kernel<<<dim3(N2 / 16, B), 512, 0, stream>>>(xyz1, xyz2, nn_idx);
  conv_kernel<<<dim3(N2 / 16, B), 256, 0, stream>>>(xyz1, feat1, xyz2, feat2,
                                                    kp, Wm, nn_idx, out);
}